// Round 9
// baseline (4523.877 us; speedup 1.0000x reference)
//
#include <hip/hip_runtime.h>
#include <stdint.h>

// SequenceDecoder: B=128, EMB=512, H=1024, V=8192, T=100 (99 sequential steps).
//  - argmax(log_softmax) == argmax(raw): recurrence needs only raw-logit argmax.
//  - fp16 hi/lo split GEMMs (3 MFMA passes, lo x2048) ~22 mantissa bits.
//  - Weights pre-converted ONCE to fp16 hi|lo tile images, LDS XOR-swizzle
//    (chunk ^= row&7) baked in. K-loop staging = global_load_lds 16B DMA.
//  - gi table precomputed (emb @ w_ih.T + b_ih); gates GEMM is h-part only
//    (K=1024), GRU fused in epilogue.
//  - PERSISTENT two-engine pipeline (r7): WGs 0-127 gates, 128-255 cls (2
//    col-tiles each). Producer-consumer relaxed flags; hpre 100-deep ring.
//  - r9: PIPELINE DEPTH. r6/r7/r8 nulls (cache path, overlap, occupancy)
//    isolated the bottleneck to per-iteration latency exposure: depth-3
//    prefetch cannot cover contended LLC/HBM latency (~1500+ cyc with 256
//    WGs in flight). Now 6 LDS buffers, 5 iterations in flight, counted
//    vmcnt at iteration top (gates 12, cls 24; drain only last 4 iters).
//    1 WG/CU (cls 144KB LDS, gates 84KB within one 146KB block).

#define Bb   128
#define EMBd 512
#define Hd   1024
#define Vd   8192
#define Td   100
#define HPB  524288   // hpre bytes per step buffer (32 st * 128 b * 128 B)

typedef __attribute__((ext_vector_type(8))) _Float16 half8;
typedef __attribute__((ext_vector_type(4))) float f32x4;
typedef unsigned long long ull;

#define LOSCALE 2048.0f
#define LOINV   (1.0f/2048.0f)

#define WAITV(N) do { asm volatile("s_waitcnt vmcnt(" #N ")" ::: "memory"); \
                      __builtin_amdgcn_sched_barrier(0); } while (0)

__device__ __forceinline__ uint32_t fkey(float f) {
  uint32_t u = __float_as_uint(f);
  return (u & 0x80000000u) ? ~u : (u | 0x80000000u);
}
__device__ __forceinline__ ull umax64(ull a, ull b) { return a > b ? a : b; }

__device__ __forceinline__ void dma16(const void* g, void* l) {
  __builtin_amdgcn_global_load_lds((const uint32_t*)g, (uint32_t*)l, 16, 0, 0);
}
// write-through 16B store (no dirty L2 line; visible at LLC once vmcnt retires)
__device__ __forceinline__ void st16sc(void* p, half8 v) {
  f32x4 d = *(f32x4*)&v;
  asm volatile("global_store_dwordx4 %0, %1, off sc0 sc1"
               :: "v"(p), "v"(d) : "memory");
}
__device__ __forceinline__ ull sysld64(const ull* p) {
  return __hip_atomic_load((ull*)p, __ATOMIC_RELAXED, __HIP_MEMORY_SCOPE_SYSTEM);
}
__device__ __forceinline__ uint32_t ld32sys(uint32_t* p) {
  return __hip_atomic_load(p, __ATOMIC_RELAXED, __HIP_MEMORY_SCOPE_SYSTEM);
}
__device__ __forceinline__ void st32sys(uint32_t* p, uint32_t v) {
  __hip_atomic_store(p, v, __ATOMIC_RELAXED, __HIP_MEMORY_SCOPE_SYSTEM);
}
__device__ __forceinline__ uint32_t add32sys(uint32_t* p, uint32_t v) {
  return __hip_atomic_fetch_add(p, v, __ATOMIC_RELAXED, __HIP_MEMORY_SCOPE_SYSTEM);
}

// split 8 fp32 into fp16 hi + (lo*2048)
__device__ __forceinline__ void cvt8(const float4 v0, const float4 v1,
                                     half8& hh, half8& ll) {
  float vv[8] = {v0.x, v0.y, v0.z, v0.w, v1.x, v1.y, v1.z, v1.w};
#pragma unroll
  for (int i = 0; i < 8; ++i) {
    _Float16 h = (_Float16)vv[i];
    hh[i] = h;
    ll[i] = (_Float16)((vv[i] - (float)h) * LOSCALE);
  }
}

// ---------------------------------------------------------------- init
// bar layout: [0]=gCnt, [1]=hReady, [8+s]=amaxCnt[s] (s=0..99), [200]=acq dummy
__global__ void k_init(const float* __restrict__ x, float* __restrict__ hbuf0,
                       ull* __restrict__ amax, char* __restrict__ hpre0,
                       uint32_t* __restrict__ bar) {
  int tid = blockIdx.x * 256 + threadIdx.x;
  if (tid < Bb * Hd) hbuf0[tid] = x[tid];
  if (tid < Td * Bb) amax[tid] = (tid < Bb) ? 0xFFFFFFFFull : 0ull;  // t=0: idx=0
  if (tid >= 16384 && tid < 16640)
    bar[tid - 16384] = (tid - 16384 == 8) ? 128u : 0u;   // amaxCnt[0]=128
  if (tid < 16384) {
    int b = tid & 127, sc = tid >> 7;
    int st = sc >> 2, c = sc & 3;
    const float* src = x + b * Hd + st * 32 + c * 8;
    float4 v0 = *(const float4*)src, v1 = *(const float4*)(src + 4);
    half8 hh, ll; cvt8(v0, v1, hh, ll);
    char* hp = hpre0 + st * 16384 + b * 128;
    *(half8*)(hp + ((c       ^ (b & 7))) * 16) = hh;
    *(half8*)(hp + (((c + 4) ^ (b & 7))) * 16) = ll;
  }
}

// ------------------------------------------------------------- prep kernels
// emb_pre: [row 8192][st_e 16][chunk 8][16B], UNSWIZZLED
__global__ void k_prep_emb(const float* __restrict__ emb, char* __restrict__ embp) {
  int t = blockIdx.x * 256 + threadIdx.x;          // 524288 total
  int row = t >> 6, rem = t & 63, st = rem >> 2, c = rem & 3;
  const float* src = emb + (size_t)row * EMBd + st * 32 + c * 8;
  float4 v0 = *(const float4*)src, v1 = *(const float4*)(src + 4);
  half8 hh, ll; cvt8(v0, v1, hh, ll);
  char* d = embp + (size_t)row * 2048 + st * 128;
  *(half8*)(d + c * 16) = hh;
  *(half8*)(d + (c + 4) * 16) = ll;
}

// wpre: per (cg,q,st) tile: [48 rows][128B], swizzled (chunk ^= r&7)
__global__ void k_prep_w(const float* __restrict__ w_ih, const float* __restrict__ w_hh,
                         char* __restrict__ wpre) {
  int bi = blockIdx.x;                 // (cg*4+q)*12+st, 3072 blocks
  int st = bi % 12, t2 = bi / 12, q = t2 & 3, cg = t2 >> 2;
  int t = threadIdx.x; if (t >= 192) return;
  int r = t >> 2, c = t & 3;
  int g = r >> 4, bn = r & 15;
  int k0 = q * 384 + st * 32 + c * 8;
  const float* src = (k0 < 512)
    ? (w_ih + (size_t)(g * 1024 + cg * 16 + bn) * EMBd + k0)
    : (w_hh + (size_t)(g * 1024 + cg * 16 + bn) * Hd + (k0 - 512));
  float4 v0 = *(const float4*)src, v1 = *(const float4*)(src + 4);
  half8 hh, ll; cvt8(v0, v1, hh, ll);
  char* d = wpre + (size_t)bi * 6144 + r * 128;
  *(half8*)(d + ((c       ^ (r & 7))) * 16) = hh;
  *(half8*)(d + (((c + 4) ^ (r & 7))) * 16) = ll;
}

// clspre: [ct 128][st 32][64 rows][128B], swizzled
__global__ void k_prep_cls(const float* __restrict__ cls_w, char* __restrict__ clsp) {
  int b = blockIdx.x;                  // ct*32+st, 4096 blocks
  int ct = b >> 5, st = b & 31;
  int t = threadIdx.x;
  int r = t >> 2, c = t & 3;
  const float* src = cls_w + (size_t)(ct * 64 + r) * Hd + st * 32 + c * 8;
  float4 v0 = *(const float4*)src, v1 = *(const float4*)(src + 4);
  half8 hh, ll; cvt8(v0, v1, hh, ll);
  char* d = clsp + (size_t)b * 8192 + r * 128;
  *(half8*)(d + ((c       ^ (r & 7))) * 16) = hh;
  *(half8*)(d + (((c + 4) ^ (r & 7))) * 16) = ll;
}

// ------------------------------------------- gi table: emb @ w_ih.T + b_ih
__global__ __launch_bounds__(256, 2) void k_prep_gi(
    const char* __restrict__ embp, const char* __restrict__ wpre,
    const float* __restrict__ b_ih, float* __restrict__ gi)
{
  const int cg = blockIdx.x, vh = blockIdx.y;
  const int tid = threadIdx.x, lane = tid & 63, w = tid >> 6;
  const int C = cg * 16;
  __shared__ __align__(16) char pA[4 * 8192];
  __shared__ __align__(16) char pB[4 * 6144];

  f32x4 accH[3], accL[3];
#pragma unroll
  for (int g = 0; g < 3; ++g) {
    accH[g] = (f32x4){0.f, 0.f, 0.f, 0.f};
    accL[g] = (f32x4){0.f, 0.f, 0.f, 0.f};
  }

  const int rr = lane >> 3, cc = lane & 7;
  const char* abase = embp + (size_t)(vh * 64 + w * 16 + rr) * 2048 + ((cc ^ rr) * 16);

  auto issue = [&](int st) {
    char* da = pA + (st & 3) * 8192 + w * 2048;
    const char* s0 = abase + st * 128;
    dma16(s0, da);
    dma16(s0 + 8 * 2048, da + 1024);
    const int wq = st / 12, wst = st - wq * 12;
    const char* sb = wpre + (size_t)((cg * 4 + wq) * 12 + wst) * 6144 + w * 1536 + lane * 16;
    char* db = pB + (st & 3) * 6144 + w * 1536;
    dma16(sb, db);
    if (lane < 32) dma16(sb + 1024, db + 1024);
  };

  const int l15 = lane & 15, qd = lane >> 4, r7 = l15 & 7;
  const int offAH = (w * 16 + l15) * 128 + ((qd)     ^ r7) * 16;
  const int offAL = (w * 16 + l15) * 128 + ((qd + 4) ^ r7) * 16;

  issue(0); issue(1); issue(2);
  WAITV(8);
  __builtin_amdgcn_s_barrier();

  for (int st = 0; st < 16; ++st) {
    const int bf = st & 3;
    half8 aH = *(half8*)&pA[bf * 8192 + offAH];
    half8 aL = *(half8*)&pA[bf * 8192 + offAL];
    if (st + 3 < 16) issue(st + 3);
#pragma unroll
    for (int g = 0; g < 3; ++g) {
      half8 bH = *(half8*)&pB[bf * 6144 + (g * 16 + l15) * 128 + ((qd)     ^ r7) * 16];
      half8 bL = *(half8*)&pB[bf * 6144 + (g * 16 + l15) * 128 + ((qd + 4) ^ r7) * 16];
      accH[g] = __builtin_amdgcn_mfma_f32_16x16x32_f16(aH, bH, accH[g], 0, 0, 0);
      accL[g] = __builtin_amdgcn_mfma_f32_16x16x32_f16(aH, bL, accL[g], 0, 0, 0);
      accL[g] = __builtin_amdgcn_mfma_f32_16x16x32_f16(aL, bH, accL[g], 0, 0, 0);
    }
    if (st < 15) {
      if (st <= 12)      { WAITV(8); }
      else if (st == 13) { WAITV(4); }
      else               { WAITV(0); }
      asm volatile("s_waitcnt lgkmcnt(0)" ::: "memory");
      __builtin_amdgcn_sched_barrier(0);
      __builtin_amdgcn_s_barrier();
    }
  }

  const int v0 = vh * 64 + w * 16 + qd * 4;
#pragma unroll
  for (int g = 0; g < 3; ++g) {
    float bi = b_ih[g * 1024 + C + l15];
#pragma unroll
    for (int i = 0; i < 4; ++i) {
      float val = accH[g][i] + accL[g][i] * LOINV + bi;
      gi[(size_t)(v0 + i) * 3072 + g * 1024 + C + l15] = val;
    }
  }
}

// ----------------------------------------------- persistent two-engine kernel
// 256 WGs, 1 WG/CU (146KB LDS). wg<128: gates (cg=wg&63, rh=wg>>6, 64rx16c).
// wg>=128: cls (64 rows x 128 cols, two 64-col tiles). 6-buffer / 5-deep
// counted-vmcnt prefetch rings on both engines.
__global__ __launch_bounds__(256) void k_loop(
    const char* __restrict__ wpre, const char* __restrict__ clsp,
    const float* __restrict__ gi,
    const float* __restrict__ b_hh, const float* __restrict__ cls_b,
    float* __restrict__ hbuf, char* __restrict__ hpre,
    ull* __restrict__ amax, float* __restrict__ out,
    uint32_t* __restrict__ bar)
{
  const int wg = blockIdx.x;
  const int tid = threadIdx.x, lane = tid & 63, w = tid >> 6;
  __shared__ __align__(16) char smem[149504];   // 146KB -> 1 WG/CU

  // once per LAUNCH: agent-scope acquire (L1+L2 inv) -> cross-launch freshness
  if (tid == 0)
    (void)__hip_atomic_load(&bar[200], __ATOMIC_ACQUIRE, __HIP_MEMORY_SCOPE_AGENT);
  __syncthreads();

  uint32_t* gCnt   = &bar[0];
  uint32_t* hReady = &bar[1];
  uint32_t* aCnt   = &bar[8];

  const int l15 = lane & 15, qd = lane >> 4, r7 = l15 & 7;
  const int offA_H = (w * 16 + l15) * 128 + ((qd)     ^ r7) * 16;
  const int offA_L = (w * 16 + l15) * 128 + ((qd + 4) ^ r7) * 16;

  if (wg < 128) {
    // =========================== GATES ENGINE ===========================
    const int cg = wg & 63, rh = wg >> 6;
    const int C = cg * 16;
    char* gA = smem;               // 6 * 8192  = 48K
    char* gB = smem + 49152;       // 6 * 6144  = 36K

    for (int s = 1; s < Td; ++s) {
      if (tid == 0)
        while (ld32sys(hReady) < (uint32_t)(s - 1)) __builtin_amdgcn_s_sleep(2);
      __syncthreads();

      const char* hsrc = hpre + (size_t)(s - 1) * HPB + rh * 8192 + w * 2048 + lane * 16;

      f32x4 accH[3], accL[3];
#pragma unroll
      for (int g = 0; g < 3; ++g) {
        accH[g] = (f32x4){0.f, 0.f, 0.f, 0.f};
        accL[g] = (f32x4){0.f, 0.f, 0.f, 0.f};
      }

      auto issue = [&](int st) {   // 3 vmem insts/wave/iter
        const int bf = st % 6;
        char* da = gA + bf * 8192 + w * 2048;
        const char* sa = hsrc + st * 16384;
        dma16(sa, da);
        dma16(sa + 1024, da + 1024);
        const int k0 = 512 + st * 32;
        const int wq = (k0 >= 1152) ? 3 : (k0 >= 768 ? 2 : 1);
        const int wst = (k0 - wq * 384) >> 5;
        const char* sb = wpre + (size_t)((cg * 4 + wq) * 12 + wst) * 6144 + w * 1536 + lane * 16;
        char* db = gB + bf * 6144 + w * 1536;
        dma16(sb, db);
        if (lane < 32) dma16(sb + 1024, db + 1024);
      };

      issue(0); issue(1); issue(2); issue(3); issue(4);

      for (int st = 0; st < 32; ++st) {
        // wait: own loads for st complete (outstanding = later iters only)
        if (st <= 27)      { WAITV(12); }
        else if (st == 28) { WAITV(9); }
        else if (st == 29) { WAITV(6); }
        else if (st == 30) { WAITV(3); }
        else               { WAITV(0); }
        __builtin_amdgcn_s_barrier();      // all waves' st loads complete

        const int bf = st % 6;
        half8 aH = *(half8*)&gA[bf * 8192 + offA_H];
        half8 aL = *(half8*)&gA[bf * 8192 + offA_L];
        if (st + 5 < 32) issue(st + 5);    // into buf (st+5)%6, disjoint
#pragma unroll
        for (int g = 0; g < 3; ++g) {
          half8 bH = *(half8*)&gB[bf * 6144 + (g * 16 + l15) * 128 + ((qd)     ^ r7) * 16];
          half8 bL = *(half8*)&gB[bf * 6144 + (g * 16 + l15) * 128 + ((qd + 4) ^ r7) * 16];
          accH[g] = __builtin_amdgcn_mfma_f32_16x16x32_f16(aH, bH, accH[g], 0, 0, 0);
          accL[g] = __builtin_amdgcn_mfma_f32_16x16x32_f16(aH, bL, accL[g], 0, 0, 0);
          accL[g] = __builtin_amdgcn_mfma_f32_16x16x32_f16(aL, bH, accL[g], 0, 0, 0);
        }
      }

      // wait: cls[s-1] finished all argmax atomics
      if (tid == 0)
        while (ld32sys(&aCnt[s - 1]) < 128u) __builtin_amdgcn_s_sleep(2);
      __syncthreads();

      // GRU epilogue: 4 rows x 1 col per lane
      const int j = C + l15;
      const float bh0 = b_hh[j], bh1 = b_hh[1024 + j], bh2 = b_hh[2048 + j];
      const float* hprev_f = hbuf + (size_t)((s - 1) & 1) * Bb * Hd;
      float* hnew_f = hbuf + (size_t)(s & 1) * Bb * Hd;
      const ull* amax_prev = amax + (size_t)(s - 1) * Bb;
      float outs[4];
#pragma unroll
      for (int i = 0; i < 4; ++i) {
        const int ri = rh * 64 + w * 16 + qd * 4 + i;
        const uint32_t idx = (~(uint32_t)sysld64(&amax_prev[ri])) & 8191u;
        const float* gp = gi + (size_t)idx * 3072 + j;
        float i_r = gp[0], i_z = gp[1024], i_n = gp[2048];
        float h_r = accH[0][i] + accL[0][i] * LOINV + bh0;
        float h_z = accH[1][i] + accL[1][i] * LOINV + bh1;
        float h_n = accH[2][i] + accL[2][i] * LOINV + bh2;
        float rr2 = 1.f / (1.f + expf(-(i_r + h_r)));
        float zz = 1.f / (1.f + expf(-(i_z + h_z)));
        float nn = tanhf(i_n + rr2 * h_n);
        float o = (1.f - zz) * nn + zz * hprev_f[ri * Hd + j];
        hnew_f[ri * Hd + j] = o;          // WG-private slice (persistent WG)
        outs[i] = o;
      }
      // transpose via LDS -> 16B write-through hpre stores
      __syncthreads();
      float* sT = (float*)smem;
#pragma unroll
      for (int i = 0; i < 4; ++i)
        sT[(w * 16 + qd * 4 + i) * 16 + l15] = outs[i];
      __syncthreads();
      if (tid < 128) {
        const int row = tid >> 1, half = tid & 1;
        const int b = rh * 64 + row;
        const float* srcp = sT + row * 16 + half * 8;
        half8 hh, ll;
#pragma unroll
        for (int e = 0; e < 8; ++e) {
          float o = srcp[e];
          _Float16 oh = (_Float16)o;
          hh[e] = oh;
          ll[e] = (_Float16)((o - (float)oh) * LOSCALE);
        }
        const int stp = C >> 5;
        const int chb = ((C & 31) >> 3) + half;
        char* hp = hpre + (size_t)s * HPB + stp * 16384 + b * 128;
        st16sc(hp + ((chb       ^ (b & 7))) * 16, hh);
        st16sc(hp + (((chb + 4) ^ (b & 7))) * 16, ll);
      }
      WAITV(0);              // hpre + hbuf stores complete
      __syncthreads();
      if (tid == 0) {
        uint32_t old = add32sys(gCnt, 1u);
        if (old + 1u == 128u * (uint32_t)s)
          st32sys(hReady, (uint32_t)s);    // releases cls[s] + gates[s+1]
      }
    }
  } else {
    // ============================ CLS ENGINE ============================
    const int wgC = wg - 128;
    const int ct2 = wgC & 63, rt0 = wgC >> 6;
    const int r0c = rt0 * 64;
    char* cA = smem;               // 6 * 8192  = 48K
    char* cB = smem + 49152;       // 6 * 16384 = 96K
    const char* bb0 = clsp + (size_t)(2 * ct2)     * 262144 + w * 2048 + lane * 16;
    const char* bb1 = clsp + (size_t)(2 * ct2 + 1) * 262144 + w * 2048 + lane * 16;

    for (int s = 1; s < Td; ++s) {
      if (tid == 0)
        while (ld32sys(hReady) < (uint32_t)s) __builtin_amdgcn_s_sleep(2);
      __syncthreads();

      const char* asrc = hpre + (size_t)s * HPB + rt0 * 8192 + w * 2048 + lane * 16;

      f32x4 accH[8], accL[8];
#pragma unroll
      for (int i = 0; i < 8; ++i) {
        accH[i] = (f32x4){0.f, 0.f, 0.f, 0.f};
        accL[i] = (f32x4){0.f, 0.f, 0.f, 0.f};
      }

      auto issue = [&](int st) {   // 6 vmem insts/wave/iter
        const int bf = st % 6;
        char* da = cA + bf * 8192 + w * 2048;
        const char* sa = asrc + st * 16384;
        dma16(sa, da);
        dma16(sa + 1024, da + 1024);
        char* db = cB + bf * 16384 + w * 2048;
        const char* s0 = bb0 + st * 8192;
        dma16(s0, db);
        dma16(s0 + 1024, db + 1024);
        const char* s1 = bb1 + st * 8192;
        dma16(s1, db + 8192);
        dma16(s1 + 1024, db + 8192 + 1024);
      };

      issue(0); issue(1); issue(2); issue(3); issue(4);

      for (int st = 0; st < 32; ++st) {
        if (st <= 27)      { WAITV(24); }
        else if (st == 28) { WAITV(18); }
        else if (st == 29) { WAITV(12); }
        else if (st == 30) { WAITV(6); }
        else               { WAITV(0); }
        __builtin_amdgcn_s_barrier();

        const int bf = st % 6;
        half8 aH = *(half8*)&cA[bf * 8192 + offA_H];
        half8 aL = *(half8*)&cA[bf * 8192 + offA_L];
        if (st + 5 < 32) issue(st + 5);
#pragma unroll
        for (int cf = 0; cf < 8; ++cf) {
          const int bo = bf * 16384 + (cf >> 2) * 8192 + ((cf & 3) * 16 + l15) * 128;
          half8 bH = *(half8*)&cB[bo + ((qd)     ^ r7) * 16];
          half8 bL = *(half8*)&cB[bo + ((qd + 4) ^ r7) * 16];
          accH[cf] = __builtin_amdgcn_mfma_f32_16x16x32_f16(aH, bH, accH[cf], 0, 0, 0);
          accL[cf] = __builtin_amdgcn_mfma_f32_16x16x32_f16(aH, bL, accL[cf], 0, 0, 0);
          accL[cf] = __builtin_amdgcn_mfma_f32_16x16x32_f16(aL, bH, accL[cf], 0, 0, 0);
        }
      }

      // epilogue: +bias, nontemporal logit stores, packed argmax atomicMax
      float bsv[8];
#pragma unroll
      for (int cf = 0; cf < 8; ++cf)
        bsv[cf] = cls_b[(2 * ct2 + (cf >> 2)) * 64 + (cf & 3) * 16 + l15];
#pragma unroll
      for (int i = 0; i < 4; ++i) {
        const int brow = r0c + w * 16 + qd * 4 + i;
        float* orow = out + ((size_t)brow * Td + s) * Vd;
        ull best = 0ull;
#pragma unroll
        for (int cf = 0; cf < 8; ++cf) {
          const int v = (2 * ct2 + (cf >> 2)) * 64 + (cf & 3) * 16 + l15;
          float val = accH[cf][i] + accL[cf][i] * LOINV + bsv[cf];
          __builtin_nontemporal_store(val, &orow[v]);
          best = umax64(best, ((ull)fkey(val) << 32) | (uint32_t)(~(uint32_t)v));
        }
        best = umax64(best, __shfl_xor(best, 1));
        best = umax64(best, __shfl_xor(best, 2));
        best = umax64(best, __shfl_xor(best, 4));
        best = umax64(best, __shfl_xor(best, 8));
        if (l15 == 0) atomicMax(&amax[(size_t)s * Bb + brow], best);
      }
      WAITV(0);              // logits + atomics complete
      __syncthreads();
      if (tid == 0) add32sys(&aCnt[s], 1u);   // releases gates[s+1] epilogue
    }
  }
}

// -------------------------------------------------- final log_softmax pass
__global__ void k_softmax(float* __restrict__ out,
                          const ull* __restrict__ amax) {
  int blk = blockIdx.x;           // 12800 = 128*100
  int t = blk % Td, b = blk / Td;
  int tid = threadIdx.x;
  float* row = out + ((size_t)b * Td + t) * Vd;
  if (t == 0) {
    float lse0 = logf(expf(1.0f) + (float)(Vd - 1));
    for (int i = tid; i < Vd; i += 256) row[i] = ((i == 0) ? 1.0f : 0.0f) - lse0;
    return;
  }
  ull key = amax[t * Bb + b];
  uint32_t ku = (uint32_t)(key >> 32);
  uint32_t u = (ku & 0x80000000u) ? (ku & 0x7fffffffu) : ~ku;
  float m = __uint_as_float(u);
  float x[32];
  float ssum = 0.f;
#pragma unroll
  for (int i = 0; i < 32; ++i) {
    x[i] = row[tid + i * 256];
    ssum += expf(x[i] - m);
  }
  ssum += __shfl_xor(ssum, 1);
  ssum += __shfl_xor(ssum, 2);
  ssum += __shfl_xor(ssum, 4);
  ssum += __shfl_xor(ssum, 8);
  ssum += __shfl_xor(ssum, 16);
  ssum += __shfl_xor(ssum, 32);
  __shared__ float wsum[4];
  if ((tid & 63) == 0) wsum[tid >> 6] = ssum;
  __syncthreads();
  float lse = m + logf(wsum[0] + wsum[1] + wsum[2] + wsum[3]);
#pragma unroll
  for (int i = 0; i < 32; ++i) row[tid + i * 256] = x[i] - lse;
}

// ----------------------------------------------------------------- launch
extern "C" void kernel_launch(void* const* d_in, const int* in_sizes, int n_in,
                              void* d_out, int out_size, void* d_ws, size_t ws_size,
                              hipStream_t stream) {
  const float* x     = (const float*)d_in[0];
  const float* emb   = (const float*)d_in[1];
  const float* w_ih  = (const float*)d_in[2];
  const float* w_hh  = (const float*)d_in[3];
  const float* b_ih  = (const float*)d_in[4];
  const float* b_hh  = (const float*)d_in[5];
  const float* cls_w = (const float*)d_in[6];
  const float* cls_b = (const float*)d_in[7];
  float* out = (float*)d_out;

  char* ws = (char*)d_ws;
  size_t o = 0;
  ull*      amax = (ull*)(ws + o);      o += (size_t)Td * Bb * 8;      // 100 KB
  uint32_t* bar  = (uint32_t*)(ws + o); o += 1024;
  float*    hbuf = (float*)(ws + o);    o += (size_t)2 * Bb * Hd * 4;  // 1 MB
  char*     hpre = ws + o;              o += (size_t)Td * HPB;         // 52.4 MB
  char*     embp = ws + o;              o += (size_t)Vd * 2048;        // 16.8 MB
  char*     wpre = ws + o;              o += (size_t)3072 * 6144;      // 18.9 MB
  char*     clsp = ws + o;              o += (size_t)128 * 32 * 8192;  // 33.6 MB
  float*    gi   = (float*)(ws + o);    o += (size_t)Vd * 3072 * 4;    // 100.7 MB

  k_init<<<512, 256, 0, stream>>>(x, hbuf, amax, hpre, bar);
  k_prep_emb<<<2048, 256, 0, stream>>>(emb, embp);
  k_prep_w<<<3072, 256, 0, stream>>>(w_ih, w_hh, wpre);
  k_prep_cls<<<4096, 256, 0, stream>>>(cls_w, clsp);
  k_prep_gi<<<dim3(64, 128), 256, 0, stream>>>(embp, wpre, b_ih, gi);

  k_loop<<<256, 256, 0, stream>>>(wpre, clsp, gi, b_hh, cls_b,
                                  hbuf, hpre, amax, out, bar);

  k_softmax<<<12800, 256, 0, stream>>>(out, amax);
}

// Round 10
// 3849.322 us; speedup vs baseline: 1.1752x; 1.1752x over previous
//
#include <hip/hip_runtime.h>
#include <stdint.h>

// SequenceDecoder: B=128, EMB=512, H=1024, V=8192, T=100 (99 sequential steps).
//  - argmax(log_softmax) == argmax(raw): recurrence needs only raw-logit argmax.
//  - fp16 hi/lo split GEMMs (3 MFMA passes, lo x2048) ~22 mantissa bits.
//  - Weights pre-converted ONCE to fp16 hi|lo tile images, LDS XOR-swizzle
//    (chunk ^= row&7) baked in. K-loop staging = global_load_lds 16B DMA.
//  - gi table precomputed (emb @ w_ih.T + b_ih); gates GEMM is h-part only
//    (K=1024), GRU fused in epilogue.
//  - PERSISTENT two-engine pipeline: WGs 0-127 gates, 128-255 cls (2 col-
//    tiles each); 6-buffer/5-deep counted-vmcnt rings; hpre 100-deep ring.
//  - r10: ATOMIC DE-SERIALIZATION. r6-r9 nulls isolated an invariant
//    ~38us/step cost. Candidate: LLC same-line atomic serialization:
//    8192 u64 atomicMax/step with 8 rows/64B line (512 serialized/line) +
//    128 fetch_adds on one gCnt line + 128 on aCnt[s]. Fix: amax padded to
//    one row per 128B (64 atomics/line, lines parallel); gCnt/aCnt become
//    16-group x 8 two-level trees (16 root atomics/step).

#define Bb   128
#define EMBd 512
#define Hd   1024
#define Vd   8192
#define Td   100
#define HPB  524288   // hpre bytes per step buffer (32 st * 128 b * 128 B)
#define AST  16       // amax row stride in ull units (128 B -> 1 row/line)

typedef __attribute__((ext_vector_type(8))) _Float16 half8;
typedef __attribute__((ext_vector_type(4))) float f32x4;
typedef unsigned long long ull;

#define LOSCALE 2048.0f
#define LOINV   (1.0f/2048.0f)

// bar layout (u32 idx): gGrp[g]=g*32 (g<16), gRoot=512, hReady=544, acq=576,
// aRoot[s]=1024+s*32, aGrp[s*16+g]=8192+(s*16+g)*32. Total < 65536 u32.
#define BAR_WORDS 65536

#define WAITV(N) do { asm volatile("s_waitcnt vmcnt(" #N ")" ::: "memory"); \
                      __builtin_amdgcn_sched_barrier(0); } while (0)

__device__ __forceinline__ uint32_t fkey(float f) {
  uint32_t u = __float_as_uint(f);
  return (u & 0x80000000u) ? ~u : (u | 0x80000000u);
}
__device__ __forceinline__ ull umax64(ull a, ull b) { return a > b ? a : b; }

__device__ __forceinline__ void dma16(const void* g, void* l) {
  __builtin_amdgcn_global_load_lds((const uint32_t*)g, (uint32_t*)l, 16, 0, 0);
}
// write-through 16B store (no dirty L2 line; visible at LLC once vmcnt retires)
__device__ __forceinline__ void st16sc(void* p, half8 v) {
  f32x4 d = *(f32x4*)&v;
  asm volatile("global_store_dwordx4 %0, %1, off sc0 sc1"
               :: "v"(p), "v"(d) : "memory");
}
__device__ __forceinline__ ull sysld64(const ull* p) {
  return __hip_atomic_load((ull*)p, __ATOMIC_RELAXED, __HIP_MEMORY_SCOPE_SYSTEM);
}
__device__ __forceinline__ uint32_t ld32sys(uint32_t* p) {
  return __hip_atomic_load(p, __ATOMIC_RELAXED, __HIP_MEMORY_SCOPE_SYSTEM);
}
__device__ __forceinline__ void st32sys(uint32_t* p, uint32_t v) {
  __hip_atomic_store(p, v, __ATOMIC_RELAXED, __HIP_MEMORY_SCOPE_SYSTEM);
}
__device__ __forceinline__ uint32_t add32sys(uint32_t* p, uint32_t v) {
  return __hip_atomic_fetch_add(p, v, __ATOMIC_RELAXED, __HIP_MEMORY_SCOPE_SYSTEM);
}

// split 8 fp32 into fp16 hi + (lo*2048)
__device__ __forceinline__ void cvt8(const float4 v0, const float4 v1,
                                     half8& hh, half8& ll) {
  float vv[8] = {v0.x, v0.y, v0.z, v0.w, v1.x, v1.y, v1.z, v1.w};
#pragma unroll
  for (int i = 0; i < 8; ++i) {
    _Float16 h = (_Float16)vv[i];
    hh[i] = h;
    ll[i] = (_Float16)((vv[i] - (float)h) * LOSCALE);
  }
}

// ---------------------------------------------------------------- init
__global__ void k_init(const float* __restrict__ x, float* __restrict__ hbuf0,
                       ull* __restrict__ amax, char* __restrict__ hpre0,
                       uint32_t* __restrict__ bar) {
  int tid = blockIdx.x * 256 + threadIdx.x;      // 131072 threads
  if (tid < Bb * Hd) hbuf0[tid] = x[tid];
  if (tid < Td * Bb)
    amax[(size_t)tid * AST] = (tid < Bb) ? 0xFFFFFFFFull : 0ull;  // t=0: idx=0
  if (tid < BAR_WORDS)
    bar[tid] = (tid == 1024) ? 16u : 0u;         // aRoot[0]=16 (step-0 done)
  if (tid < 16384) {
    int b = tid & 127, sc = tid >> 7;
    int st = sc >> 2, c = sc & 3;
    const float* src = x + b * Hd + st * 32 + c * 8;
    float4 v0 = *(const float4*)src, v1 = *(const float4*)(src + 4);
    half8 hh, ll; cvt8(v0, v1, hh, ll);
    char* hp = hpre0 + st * 16384 + b * 128;
    *(half8*)(hp + ((c       ^ (b & 7))) * 16) = hh;
    *(half8*)(hp + (((c + 4) ^ (b & 7))) * 16) = ll;
  }
}

// ------------------------------------------------------------- prep kernels
// emb_pre: [row 8192][st_e 16][chunk 8][16B], UNSWIZZLED
__global__ void k_prep_emb(const float* __restrict__ emb, char* __restrict__ embp) {
  int t = blockIdx.x * 256 + threadIdx.x;          // 524288 total
  int row = t >> 6, rem = t & 63, st = rem >> 2, c = rem & 3;
  const float* src = emb + (size_t)row * EMBd + st * 32 + c * 8;
  float4 v0 = *(const float4*)src, v1 = *(const float4*)(src + 4);
  half8 hh, ll; cvt8(v0, v1, hh, ll);
  char* d = embp + (size_t)row * 2048 + st * 128;
  *(half8*)(d + c * 16) = hh;
  *(half8*)(d + (c + 4) * 16) = ll;
}

// wpre: per (cg,q,st) tile: [48 rows][128B], swizzled (chunk ^= r&7)
__global__ void k_prep_w(const float* __restrict__ w_ih, const float* __restrict__ w_hh,
                         char* __restrict__ wpre) {
  int bi = blockIdx.x;                 // (cg*4+q)*12+st, 3072 blocks
  int st = bi % 12, t2 = bi / 12, q = t2 & 3, cg = t2 >> 2;
  int t = threadIdx.x; if (t >= 192) return;
  int r = t >> 2, c = t & 3;
  int g = r >> 4, bn = r & 15;
  int k0 = q * 384 + st * 32 + c * 8;
  const float* src = (k0 < 512)
    ? (w_ih + (size_t)(g * 1024 + cg * 16 + bn) * EMBd + k0)
    : (w_hh + (size_t)(g * 1024 + cg * 16 + bn) * Hd + (k0 - 512));
  float4 v0 = *(const float4*)src, v1 = *(const float4*)(src + 4);
  half8 hh, ll; cvt8(v0, v1, hh, ll);
  char* d = wpre + (size_t)bi * 6144 + r * 128;
  *(half8*)(d + ((c       ^ (r & 7))) * 16) = hh;
  *(half8*)(d + (((c + 4) ^ (r & 7))) * 16) = ll;
}

// clspre: [ct 128][st 32][64 rows][128B], swizzled
__global__ void k_prep_cls(const float* __restrict__ cls_w, char* __restrict__ clsp) {
  int b = blockIdx.x;                  // ct*32+st, 4096 blocks
  int ct = b >> 5, st = b & 31;
  int t = threadIdx.x;
  int r = t >> 2, c = t & 3;
  const float* src = cls_w + (size_t)(ct * 64 + r) * Hd + st * 32 + c * 8;
  float4 v0 = *(const float4*)src, v1 = *(const float4*)(src + 4);
  half8 hh, ll; cvt8(v0, v1, hh, ll);
  char* d = clsp + (size_t)b * 8192 + r * 128;
  *(half8*)(d + ((c       ^ (r & 7))) * 16) = hh;
  *(half8*)(d + (((c + 4) ^ (r & 7))) * 16) = ll;
}

// ------------------------------------------- gi table: emb @ w_ih.T + b_ih
__global__ __launch_bounds__(256, 2) void k_prep_gi(
    const char* __restrict__ embp, const char* __restrict__ wpre,
    const float* __restrict__ b_ih, float* __restrict__ gi)
{
  const int cg = blockIdx.x, vh = blockIdx.y;
  const int tid = threadIdx.x, lane = tid & 63, w = tid >> 6;
  const int C = cg * 16;
  __shared__ __align__(16) char pA[4 * 8192];
  __shared__ __align__(16) char pB[4 * 6144];

  f32x4 accH[3], accL[3];
#pragma unroll
  for (int g = 0; g < 3; ++g) {
    accH[g] = (f32x4){0.f, 0.f, 0.f, 0.f};
    accL[g] = (f32x4){0.f, 0.f, 0.f, 0.f};
  }

  const int rr = lane >> 3, cc = lane & 7;
  const char* abase = embp + (size_t)(vh * 64 + w * 16 + rr) * 2048 + ((cc ^ rr) * 16);

  auto issue = [&](int st) {
    char* da = pA + (st & 3) * 8192 + w * 2048;
    const char* s0 = abase + st * 128;
    dma16(s0, da);
    dma16(s0 + 8 * 2048, da + 1024);
    const int wq = st / 12, wst = st - wq * 12;
    const char* sb = wpre + (size_t)((cg * 4 + wq) * 12 + wst) * 6144 + w * 1536 + lane * 16;
    char* db = pB + (st & 3) * 6144 + w * 1536;
    dma16(sb, db);
    if (lane < 32) dma16(sb + 1024, db + 1024);
  };

  const int l15 = lane & 15, qd = lane >> 4, r7 = l15 & 7;
  const int offAH = (w * 16 + l15) * 128 + ((qd)     ^ r7) * 16;
  const int offAL = (w * 16 + l15) * 128 + ((qd + 4) ^ r7) * 16;

  issue(0); issue(1); issue(2);
  WAITV(8);
  __builtin_amdgcn_s_barrier();

  for (int st = 0; st < 16; ++st) {
    const int bf = st & 3;
    half8 aH = *(half8*)&pA[bf * 8192 + offAH];
    half8 aL = *(half8*)&pA[bf * 8192 + offAL];
    if (st + 3 < 16) issue(st + 3);
#pragma unroll
    for (int g = 0; g < 3; ++g) {
      half8 bH = *(half8*)&pB[bf * 6144 + (g * 16 + l15) * 128 + ((qd)     ^ r7) * 16];
      half8 bL = *(half8*)&pB[bf * 6144 + (g * 16 + l15) * 128 + ((qd + 4) ^ r7) * 16];
      accH[g] = __builtin_amdgcn_mfma_f32_16x16x32_f16(aH, bH, accH[g], 0, 0, 0);
      accL[g] = __builtin_amdgcn_mfma_f32_16x16x32_f16(aH, bL, accL[g], 0, 0, 0);
      accL[g] = __builtin_amdgcn_mfma_f32_16x16x32_f16(aL, bH, accL[g], 0, 0, 0);
    }
    if (st < 15) {
      if (st <= 12)      { WAITV(8); }
      else if (st == 13) { WAITV(4); }
      else               { WAITV(0); }
      asm volatile("s_waitcnt lgkmcnt(0)" ::: "memory");
      __builtin_amdgcn_sched_barrier(0);
      __builtin_amdgcn_s_barrier();
    }
  }

  const int v0 = vh * 64 + w * 16 + qd * 4;
#pragma unroll
  for (int g = 0; g < 3; ++g) {
    float bi = b_ih[g * 1024 + C + l15];
#pragma unroll
    for (int i = 0; i < 4; ++i) {
      float val = accH[g][i] + accL[g][i] * LOINV + bi;
      gi[(size_t)(v0 + i) * 3072 + g * 1024 + C + l15] = val;
    }
  }
}

// ----------------------------------------------- persistent two-engine kernel
__global__ __launch_bounds__(256) void k_loop(
    const char* __restrict__ wpre, const char* __restrict__ clsp,
    const float* __restrict__ gi,
    const float* __restrict__ b_hh, const float* __restrict__ cls_b,
    float* __restrict__ hbuf, char* __restrict__ hpre,
    ull* __restrict__ amax, float* __restrict__ out,
    uint32_t* __restrict__ bar)
{
  const int wg = blockIdx.x;
  const int tid = threadIdx.x, lane = tid & 63, w = tid >> 6;
  __shared__ __align__(16) char smem[149504];   // 146KB -> 1 WG/CU

  // once per LAUNCH: agent-scope acquire (L1+L2 inv) -> cross-launch freshness
  if (tid == 0)
    (void)__hip_atomic_load(&bar[576], __ATOMIC_ACQUIRE, __HIP_MEMORY_SCOPE_AGENT);
  __syncthreads();

  uint32_t* hReady = &bar[544];

  const int l15 = lane & 15, qd = lane >> 4, r7 = l15 & 7;
  const int offA_H = (w * 16 + l15) * 128 + ((qd)     ^ r7) * 16;
  const int offA_L = (w * 16 + l15) * 128 + ((qd + 4) ^ r7) * 16;

  if (wg < 128) {
    // =========================== GATES ENGINE ===========================
    const int cg = wg & 63, rh = wg >> 6;
    const int C = cg * 16;
    char* gA = smem;               // 6 * 8192  = 48K
    char* gB = smem + 49152;       // 6 * 6144  = 36K

    for (int s = 1; s < Td; ++s) {
      if (tid == 0)
        while (ld32sys(hReady) < (uint32_t)(s - 1)) __builtin_amdgcn_s_sleep(2);
      __syncthreads();

      const char* hsrc = hpre + (size_t)(s - 1) * HPB + rh * 8192 + w * 2048 + lane * 16;

      f32x4 accH[3], accL[3];
#pragma unroll
      for (int g = 0; g < 3; ++g) {
        accH[g] = (f32x4){0.f, 0.f, 0.f, 0.f};
        accL[g] = (f32x4){0.f, 0.f, 0.f, 0.f};
      }

      auto issue = [&](int st) {   // 3 vmem insts/wave/iter
        const int bf = st % 6;
        char* da = gA + bf * 8192 + w * 2048;
        const char* sa = hsrc + st * 16384;
        dma16(sa, da);
        dma16(sa + 1024, da + 1024);
        const int k0 = 512 + st * 32;
        const int wq = (k0 >= 1152) ? 3 : (k0 >= 768 ? 2 : 1);
        const int wst = (k0 - wq * 384) >> 5;
        const char* sb = wpre + (size_t)((cg * 4 + wq) * 12 + wst) * 6144 + w * 1536 + lane * 16;
        char* db = gB + bf * 6144 + w * 1536;
        dma16(sb, db);
        if (lane < 32) dma16(sb + 1024, db + 1024);
      };

      issue(0); issue(1); issue(2); issue(3); issue(4);

      for (int st = 0; st < 32; ++st) {
        if (st <= 27)      { WAITV(12); }
        else if (st == 28) { WAITV(9); }
        else if (st == 29) { WAITV(6); }
        else if (st == 30) { WAITV(3); }
        else               { WAITV(0); }
        __builtin_amdgcn_s_barrier();

        const int bf = st % 6;
        half8 aH = *(half8*)&gA[bf * 8192 + offA_H];
        half8 aL = *(half8*)&gA[bf * 8192 + offA_L];
        if (st + 5 < 32) issue(st + 5);
#pragma unroll
        for (int g = 0; g < 3; ++g) {
          half8 bH = *(half8*)&gB[bf * 6144 + (g * 16 + l15) * 128 + ((qd)     ^ r7) * 16];
          half8 bL = *(half8*)&gB[bf * 6144 + (g * 16 + l15) * 128 + ((qd + 4) ^ r7) * 16];
          accH[g] = __builtin_amdgcn_mfma_f32_16x16x32_f16(aH, bH, accH[g], 0, 0, 0);
          accL[g] = __builtin_amdgcn_mfma_f32_16x16x32_f16(aH, bL, accL[g], 0, 0, 0);
          accL[g] = __builtin_amdgcn_mfma_f32_16x16x32_f16(aL, bH, accL[g], 0, 0, 0);
        }
      }

      // wait: cls[s-1] argmax complete (tree root == 16 groups)
      if (tid == 0)
        while (ld32sys(&bar[1024 + (s - 1) * 32]) < 16u) __builtin_amdgcn_s_sleep(2);
      __syncthreads();

      // GRU epilogue: 4 rows x 1 col per lane
      const int j = C + l15;
      const float bh0 = b_hh[j], bh1 = b_hh[1024 + j], bh2 = b_hh[2048 + j];
      const float* hprev_f = hbuf + (size_t)((s - 1) & 1) * Bb * Hd;
      float* hnew_f = hbuf + (size_t)(s & 1) * Bb * Hd;
      const ull* amax_prev = amax + (size_t)(s - 1) * Bb * AST;
      float outs[4];
#pragma unroll
      for (int i = 0; i < 4; ++i) {
        const int ri = rh * 64 + w * 16 + qd * 4 + i;
        const uint32_t idx = (~(uint32_t)sysld64(&amax_prev[(size_t)ri * AST])) & 8191u;
        const float* gp = gi + (size_t)idx * 3072 + j;
        float i_r = gp[0], i_z = gp[1024], i_n = gp[2048];
        float h_r = accH[0][i] + accL[0][i] * LOINV + bh0;
        float h_z = accH[1][i] + accL[1][i] * LOINV + bh1;
        float h_n = accH[2][i] + accL[2][i] * LOINV + bh2;
        float rr2 = 1.f / (1.f + expf(-(i_r + h_r)));
        float zz = 1.f / (1.f + expf(-(i_z + h_z)));
        float nn = tanhf(i_n + rr2 * h_n);
        float o = (1.f - zz) * nn + zz * hprev_f[ri * Hd + j];
        hnew_f[ri * Hd + j] = o;          // WG-private slice (persistent WG)
        outs[i] = o;
      }
      // transpose via LDS -> 16B write-through hpre stores
      __syncthreads();
      float* sT = (float*)smem;
#pragma unroll
      for (int i = 0; i < 4; ++i)
        sT[(w * 16 + qd * 4 + i) * 16 + l15] = outs[i];
      __syncthreads();
      if (tid < 128) {
        const int row = tid >> 1, half = tid & 1;
        const int b = rh * 64 + row;
        const float* srcp = sT + row * 16 + half * 8;
        half8 hh, ll;
#pragma unroll
        for (int e = 0; e < 8; ++e) {
          float o = srcp[e];
          _Float16 oh = (_Float16)o;
          hh[e] = oh;
          ll[e] = (_Float16)((o - (float)oh) * LOSCALE);
        }
        const int stp = C >> 5;
        const int chb = ((C & 31) >> 3) + half;
        char* hp = hpre + (size_t)s * HPB + stp * 16384 + b * 128;
        st16sc(hp + ((chb       ^ (b & 7))) * 16, hh);
        st16sc(hp + (((chb + 4) ^ (b & 7))) * 16, ll);
      }
      WAITV(0);              // hpre + hbuf stores complete
      __syncthreads();
      if (tid == 0) {
        // two-level completion tree: 16 groups of 8 -> root -> hReady
        uint32_t old = add32sys(&bar[(wg >> 3) * 32], 1u);
        if (old + 1u == 8u * (uint32_t)s) {
          uint32_t o2 = add32sys(&bar[512], 1u);
          if (o2 + 1u == 16u * (uint32_t)s)
            st32sys(hReady, (uint32_t)s);   // releases cls[s] + gates[s+1]
        }
      }
    }
  } else {
    // ============================ CLS ENGINE ============================
    const int wgC = wg - 128;
    const int ct2 = wgC & 63, rt0 = wgC >> 6;
    const int r0c = rt0 * 64;
    char* cA = smem;               // 6 * 8192  = 48K
    char* cB = smem + 49152;       // 6 * 16384 = 96K
    const char* bb0 = clsp + (size_t)(2 * ct2)     * 262144 + w * 2048 + lane * 16;
    const char* bb1 = clsp + (size_t)(2 * ct2 + 1) * 262144 + w * 2048 + lane * 16;

    for (int s = 1; s < Td; ++s) {
      if (tid == 0)
        while (ld32sys(hReady) < (uint32_t)s) __builtin_amdgcn_s_sleep(2);
      __syncthreads();

      const char* asrc = hpre + (size_t)s * HPB + rt0 * 8192 + w * 2048 + lane * 16;

      f32x4 accH[8], accL[8];
#pragma unroll
      for (int i = 0; i < 8; ++i) {
        accH[i] = (f32x4){0.f, 0.f, 0.f, 0.f};
        accL[i] = (f32x4){0.f, 0.f, 0.f, 0.f};
      }

      auto issue = [&](int st) {   // 6 vmem insts/wave/iter
        const int bf = st % 6;
        char* da = cA + bf * 8192 + w * 2048;
        const char* sa = asrc + st * 16384;
        dma16(sa, da);
        dma16(sa + 1024, da + 1024);
        char* db = cB + bf * 16384 + w * 2048;
        const char* s0 = bb0 + st * 8192;
        dma16(s0, db);
        dma16(s0 + 1024, db + 1024);
        const char* s1 = bb1 + st * 8192;
        dma16(s1, db + 8192);
        dma16(s1 + 1024, db + 8192 + 1024);
      };

      issue(0); issue(1); issue(2); issue(3); issue(4);

      for (int st = 0; st < 32; ++st) {
        if (st <= 27)      { WAITV(24); }
        else if (st == 28) { WAITV(18); }
        else if (st == 29) { WAITV(12); }
        else if (st == 30) { WAITV(6); }
        else               { WAITV(0); }
        __builtin_amdgcn_s_barrier();

        const int bf = st % 6;
        half8 aH = *(half8*)&cA[bf * 8192 + offA_H];
        half8 aL = *(half8*)&cA[bf * 8192 + offA_L];
        if (st + 5 < 32) issue(st + 5);
#pragma unroll
        for (int cf = 0; cf < 8; ++cf) {
          const int bo = bf * 16384 + (cf >> 2) * 8192 + ((cf & 3) * 16 + l15) * 128;
          half8 bH = *(half8*)&cB[bo + ((qd)     ^ r7) * 16];
          half8 bL = *(half8*)&cB[bo + ((qd + 4) ^ r7) * 16];
          accH[cf] = __builtin_amdgcn_mfma_f32_16x16x32_f16(aH, bH, accH[cf], 0, 0, 0);
          accL[cf] = __builtin_amdgcn_mfma_f32_16x16x32_f16(aH, bL, accL[cf], 0, 0, 0);
          accL[cf] = __builtin_amdgcn_mfma_f32_16x16x32_f16(aL, bH, accL[cf], 0, 0, 0);
        }
      }

      // epilogue: +bias, nontemporal logit stores, packed argmax atomicMax
      // (amax rows padded to 128B lines -> per-line serialization 64 not 512)
      float bsv[8];
#pragma unroll
      for (int cf = 0; cf < 8; ++cf)
        bsv[cf] = cls_b[(2 * ct2 + (cf >> 2)) * 64 + (cf & 3) * 16 + l15];
#pragma unroll
      for (int i = 0; i < 4; ++i) {
        const int brow = r0c + w * 16 + qd * 4 + i;
        float* orow = out + ((size_t)brow * Td + s) * Vd;
        ull best = 0ull;
#pragma unroll
        for (int cf = 0; cf < 8; ++cf) {
          const int v = (2 * ct2 + (cf >> 2)) * 64 + (cf & 3) * 16 + l15;
          float val = accH[cf][i] + accL[cf][i] * LOINV + bsv[cf];
          __builtin_nontemporal_store(val, &orow[v]);
          best = umax64(best, ((ull)fkey(val) << 32) | (uint32_t)(~(uint32_t)v));
        }
        best = umax64(best, __shfl_xor(best, 1));
        best = umax64(best, __shfl_xor(best, 2));
        best = umax64(best, __shfl_xor(best, 4));
        best = umax64(best, __shfl_xor(best, 8));
        if (l15 == 0)
          atomicMax(&amax[((size_t)s * Bb + brow) * AST], best);
      }
      WAITV(0);              // logits + atomics complete
      __syncthreads();
      if (tid == 0) {
        // two-level: 16 groups of 8 -> aRoot[s]
        uint32_t old = add32sys(&bar[8192 + ((s * 16) + (wgC >> 3)) * 32], 1u);
        if (old + 1u == 8u)
          add32sys(&bar[1024 + s * 32], 1u);   // aRoot[s] -> 16 when done
      }
    }
  }
}

// -------------------------------------------------- final log_softmax pass
__global__ void k_softmax(float* __restrict__ out,
                          const ull* __restrict__ amax) {
  int blk = blockIdx.x;           // 12800 = 128*100
  int t = blk % Td, b = blk / Td;
  int tid = threadIdx.x;
  float* row = out + ((size_t)b * Td + t) * Vd;
  if (t == 0) {
    float lse0 = logf(expf(1.0f) + (float)(Vd - 1));
    for (int i = tid; i < Vd; i += 256) row[i] = ((i == 0) ? 1.0f : 0.0f) - lse0;
    return;
  }
  ull key = amax[((size_t)t * Bb + b) * AST];
  uint32_t ku = (uint32_t)(key >> 32);
  uint32_t u = (ku & 0x80000000u) ? (ku & 0x7fffffffu) : ~ku;
  float m = __uint_as_float(u);
  float x[32];
  float ssum = 0.f;
#pragma unroll
  for (int i = 0; i < 32; ++i) {
    x[i] = row[tid + i * 256];
    ssum += expf(x[i] - m);
  }
  ssum += __shfl_xor(ssum, 1);
  ssum += __shfl_xor(ssum, 2);
  ssum += __shfl_xor(ssum, 4);
  ssum += __shfl_xor(ssum, 8);
  ssum += __shfl_xor(ssum, 16);
  ssum += __shfl_xor(ssum, 32);
  __shared__ float wsum[4];
  if ((tid & 63) == 0) wsum[tid >> 6] = ssum;
  __syncthreads();
  float lse = m + logf(wsum[0] + wsum[1] + wsum[2] + wsum[3]);
#pragma unroll
  for (int i = 0; i < 32; ++i) row[tid + i * 256] = x[i] - lse;
}

// ----------------------------------------------------------------- launch
extern "C" void kernel_launch(void* const* d_in, const int* in_sizes, int n_in,
                              void* d_out, int out_size, void* d_ws, size_t ws_size,
                              hipStream_t stream) {
  const float* x     = (const float*)d_in[0];
  const float* emb   = (const float*)d_in[1];
  const float* w_ih  = (const float*)d_in[2];
  const float* w_hh  = (const float*)d_in[3];
  const float* b_ih  = (const float*)d_in[4];
  const float* b_hh  = (const float*)d_in[5];
  const float* cls_w = (const float*)d_in[6];
  const float* cls_b = (const float*)d_in[7];
  float* out = (float*)d_out;

  char* ws = (char*)d_ws;
  size_t o = 0;
  ull*      amax = (ull*)(ws + o);      o += (size_t)Td * Bb * AST * 8;  // 1.64 MB
  uint32_t* bar  = (uint32_t*)(ws + o); o += (size_t)BAR_WORDS * 4;     // 256 KB
  float*    hbuf = (float*)(ws + o);    o += (size_t)2 * Bb * Hd * 4;   // 1 MB
  char*     hpre = ws + o;              o += (size_t)Td * HPB;          // 52.4 MB
  char*     embp = ws + o;              o += (size_t)Vd * 2048;         // 16.8 MB
  char*     wpre = ws + o;              o += (size_t)3072 * 6144;       // 18.9 MB
  char*     clsp = ws + o;              o += (size_t)128 * 32 * 8192;   // 33.6 MB
  float*    gi   = (float*)(ws + o);    o += (size_t)Vd * 3072 * 4;     // 100.7 MB

  k_init<<<512, 256, 0, stream>>>(x, hbuf, amax, hpre, bar);
  k_prep_emb<<<2048, 256, 0, stream>>>(emb, embp);
  k_prep_w<<<3072, 256, 0, stream>>>(w_ih, w_hh, wpre);
  k_prep_cls<<<4096, 256, 0, stream>>>(cls_w, clsp);
  k_prep_gi<<<dim3(64, 128), 256, 0, stream>>>(embp, wpre, b_ih, gi);

  k_loop<<<256, 256, 0, stream>>>(wpre, clsp, gi, b_hh, cls_b,
                                  hbuf, hpre, amax, out, bar);

  k_softmax<<<12800, 256, 0, stream>>>(out, amax);
}

// Round 11
// 3708.517 us; speedup vs baseline: 1.2199x; 1.0380x over previous
//
#include <hip/hip_runtime.h>
#include <stdint.h>

// SequenceDecoder: B=128, EMB=512, H=1024, V=8192, T=100 (99 sequential steps).
//  - argmax(log_softmax) == argmax(raw): recurrence needs only raw-logit argmax.
//  - fp16 hi/lo split GEMMs (3 MFMA passes, lo x2048) ~22 mantissa bits.
//  - Weights pre-converted ONCE to fp16 hi|lo tile images, LDS XOR-swizzle
//    (chunk ^= row&7) baked in. K-loop staging = global_load_lds 16B DMA.
//  - gi table precomputed (emb @ w_ih.T + b_ih); gates GEMM is h-part only
//    (K=1024), GRU fused in epilogue.
//  - PERSISTENT two-engine pipeline: WGs 0-127 gates, 128-255 cls (2 col-
//    tiles each); 6-buffer/5-deep counted-vmcnt rings; hpre 100-deep ring.
//  - r10 (kept): amax padding + two-level completion trees (-18%, confirmed
//    "serialized LLC ops on critical path" theory).
//  - r11: ATOMIC-FREE ARGMAX. The remaining 8192 u64 atomicMax/step (64-deep
//    serialized per row-line) replaced by plain sc0sc1 candidate stores to
//    cand[s][row][ct2]; gates engine (already waiting on aCnt) reduces the
//    64 candidates per row cooperatively (coalesced 32KB read + shfl). The
//    reduced key IS the argmax -> GRU's LLC-bypass idx load removed; amax
//    array deleted (k_softmax reduces cand[t][b][*] directly).

#define Bb   128
#define EMBd 512
#define Hd   1024
#define Vd   8192
#define Td   100
#define HPB  524288   // hpre bytes per step buffer (32 st * 128 b * 128 B)

typedef __attribute__((ext_vector_type(8))) _Float16 half8;
typedef __attribute__((ext_vector_type(4))) float f32x4;
typedef unsigned long long ull;

#define LOSCALE 2048.0f
#define LOINV   (1.0f/2048.0f)

// bar layout (u32 idx): gGrp[g]=g*32 (g<16), gRoot=512, hReady=544, acq=576,
// aRoot[s]=1024+s*32, aGrp[s*16+g]=8192+(s*16+g)*32. Total < 65536 u32.
#define BAR_WORDS 65536

#define WAITV(N) do { asm volatile("s_waitcnt vmcnt(" #N ")" ::: "memory"); \
                      __builtin_amdgcn_sched_barrier(0); } while (0)

__device__ __forceinline__ uint32_t fkey(float f) {
  uint32_t u = __float_as_uint(f);
  return (u & 0x80000000u) ? ~u : (u | 0x80000000u);
}
__device__ __forceinline__ ull umax64(ull a, ull b) { return a > b ? a : b; }

__device__ __forceinline__ void dma16(const void* g, void* l) {
  __builtin_amdgcn_global_load_lds((const uint32_t*)g, (uint32_t*)l, 16, 0, 0);
}
// write-through 16B store (no dirty L2 line; visible at LLC once vmcnt retires)
__device__ __forceinline__ void st16sc(void* p, half8 v) {
  f32x4 d = *(f32x4*)&v;
  asm volatile("global_store_dwordx4 %0, %1, off sc0 sc1"
               :: "v"(p), "v"(d) : "memory");
}
// write-through 8B store (argmax candidate slots)
__device__ __forceinline__ void st8sc(void* p, ull v) {
  asm volatile("global_store_dwordx2 %0, %1, off sc0 sc1"
               :: "v"(p), "v"(v) : "memory");
}
__device__ __forceinline__ uint32_t ld32sys(uint32_t* p) {
  return __hip_atomic_load(p, __ATOMIC_RELAXED, __HIP_MEMORY_SCOPE_SYSTEM);
}
__device__ __forceinline__ void st32sys(uint32_t* p, uint32_t v) {
  __hip_atomic_store(p, v, __ATOMIC_RELAXED, __HIP_MEMORY_SCOPE_SYSTEM);
}
__device__ __forceinline__ uint32_t add32sys(uint32_t* p, uint32_t v) {
  return __hip_atomic_fetch_add(p, v, __ATOMIC_RELAXED, __HIP_MEMORY_SCOPE_SYSTEM);
}

// split 8 fp32 into fp16 hi + (lo*2048)
__device__ __forceinline__ void cvt8(const float4 v0, const float4 v1,
                                     half8& hh, half8& ll) {
  float vv[8] = {v0.x, v0.y, v0.z, v0.w, v1.x, v1.y, v1.z, v1.w};
#pragma unroll
  for (int i = 0; i < 8; ++i) {
    _Float16 h = (_Float16)vv[i];
    hh[i] = h;
    ll[i] = (_Float16)((vv[i] - (float)h) * LOSCALE);
  }
}

// ---------------------------------------------------------------- init
__global__ void k_init(const float* __restrict__ x, float* __restrict__ hbuf0,
                       ull* __restrict__ cand, char* __restrict__ hpre0,
                       uint32_t* __restrict__ bar) {
  int tid = blockIdx.x * 256 + threadIdx.x;      // 131072 threads
  if (tid < Bb * Hd) hbuf0[tid] = x[tid];
  // cand[0][b][slot]: slot 0 encodes idx=0 (key value 0, ~v = 0xFFFFFFFF)
  if (tid < Bb * 64) cand[tid] = ((tid & 63) == 0) ? 0xFFFFFFFFull : 0ull;
  if (tid < BAR_WORDS)
    bar[tid] = (tid == 1024) ? 16u : 0u;         // aRoot[0]=16 (step-0 done)
  if (tid < 16384) {
    int b = tid & 127, sc = tid >> 7;
    int st = sc >> 2, c = sc & 3;
    const float* src = x + b * Hd + st * 32 + c * 8;
    float4 v0 = *(const float4*)src, v1 = *(const float4*)(src + 4);
    half8 hh, ll; cvt8(v0, v1, hh, ll);
    char* hp = hpre0 + st * 16384 + b * 128;
    *(half8*)(hp + ((c       ^ (b & 7))) * 16) = hh;
    *(half8*)(hp + (((c + 4) ^ (b & 7))) * 16) = ll;
  }
}

// ------------------------------------------------------------- prep kernels
// emb_pre: [row 8192][st_e 16][chunk 8][16B], UNSWIZZLED
__global__ void k_prep_emb(const float* __restrict__ emb, char* __restrict__ embp) {
  int t = blockIdx.x * 256 + threadIdx.x;          // 524288 total
  int row = t >> 6, rem = t & 63, st = rem >> 2, c = rem & 3;
  const float* src = emb + (size_t)row * EMBd + st * 32 + c * 8;
  float4 v0 = *(const float4*)src, v1 = *(const float4*)(src + 4);
  half8 hh, ll; cvt8(v0, v1, hh, ll);
  char* d = embp + (size_t)row * 2048 + st * 128;
  *(half8*)(d + c * 16) = hh;
  *(half8*)(d + (c + 4) * 16) = ll;
}

// wpre: per (cg,q,st) tile: [48 rows][128B], swizzled (chunk ^= r&7)
__global__ void k_prep_w(const float* __restrict__ w_ih, const float* __restrict__ w_hh,
                         char* __restrict__ wpre) {
  int bi = blockIdx.x;                 // (cg*4+q)*12+st, 3072 blocks
  int st = bi % 12, t2 = bi / 12, q = t2 & 3, cg = t2 >> 2;
  int t = threadIdx.x; if (t >= 192) return;
  int r = t >> 2, c = t & 3;
  int g = r >> 4, bn = r & 15;
  int k0 = q * 384 + st * 32 + c * 8;
  const float* src = (k0 < 512)
    ? (w_ih + (size_t)(g * 1024 + cg * 16 + bn) * EMBd + k0)
    : (w_hh + (size_t)(g * 1024 + cg * 16 + bn) * Hd + (k0 - 512));
  float4 v0 = *(const float4*)src, v1 = *(const float4*)(src + 4);
  half8 hh, ll; cvt8(v0, v1, hh, ll);
  char* d = wpre + (size_t)bi * 6144 + r * 128;
  *(half8*)(d + ((c       ^ (r & 7))) * 16) = hh;
  *(half8*)(d + (((c + 4) ^ (r & 7))) * 16) = ll;
}

// clspre: [ct 128][st 32][64 rows][128B], swizzled
__global__ void k_prep_cls(const float* __restrict__ cls_w, char* __restrict__ clsp) {
  int b = blockIdx.x;                  // ct*32+st, 4096 blocks
  int ct = b >> 5, st = b & 31;
  int t = threadIdx.x;
  int r = t >> 2, c = t & 3;
  const float* src = cls_w + (size_t)(ct * 64 + r) * Hd + st * 32 + c * 8;
  float4 v0 = *(const float4*)src, v1 = *(const float4*)(src + 4);
  half8 hh, ll; cvt8(v0, v1, hh, ll);
  char* d = clsp + (size_t)b * 8192 + r * 128;
  *(half8*)(d + ((c       ^ (r & 7))) * 16) = hh;
  *(half8*)(d + (((c + 4) ^ (r & 7))) * 16) = ll;
}

// ------------------------------------------- gi table: emb @ w_ih.T + b_ih
__global__ __launch_bounds__(256, 2) void k_prep_gi(
    const char* __restrict__ embp, const char* __restrict__ wpre,
    const float* __restrict__ b_ih, float* __restrict__ gi)
{
  const int cg = blockIdx.x, vh = blockIdx.y;
  const int tid = threadIdx.x, lane = tid & 63, w = tid >> 6;
  const int C = cg * 16;
  __shared__ __align__(16) char pA[4 * 8192];
  __shared__ __align__(16) char pB[4 * 6144];

  f32x4 accH[3], accL[3];
#pragma unroll
  for (int g = 0; g < 3; ++g) {
    accH[g] = (f32x4){0.f, 0.f, 0.f, 0.f};
    accL[g] = (f32x4){0.f, 0.f, 0.f, 0.f};
  }

  const int rr = lane >> 3, cc = lane & 7;
  const char* abase = embp + (size_t)(vh * 64 + w * 16 + rr) * 2048 + ((cc ^ rr) * 16);

  auto issue = [&](int st) {
    char* da = pA + (st & 3) * 8192 + w * 2048;
    const char* s0 = abase + st * 128;
    dma16(s0, da);
    dma16(s0 + 8 * 2048, da + 1024);
    const int wq = st / 12, wst = st - wq * 12;
    const char* sb = wpre + (size_t)((cg * 4 + wq) * 12 + wst) * 6144 + w * 1536 + lane * 16;
    char* db = pB + (st & 3) * 6144 + w * 1536;
    dma16(sb, db);
    if (lane < 32) dma16(sb + 1024, db + 1024);
  };

  const int l15 = lane & 15, qd = lane >> 4, r7 = l15 & 7;
  const int offAH = (w * 16 + l15) * 128 + ((qd)     ^ r7) * 16;
  const int offAL = (w * 16 + l15) * 128 + ((qd + 4) ^ r7) * 16;

  issue(0); issue(1); issue(2);
  WAITV(8);
  __builtin_amdgcn_s_barrier();

  for (int st = 0; st < 16; ++st) {
    const int bf = st & 3;
    half8 aH = *(half8*)&pA[bf * 8192 + offAH];
    half8 aL = *(half8*)&pA[bf * 8192 + offAL];
    if (st + 3 < 16) issue(st + 3);
#pragma unroll
    for (int g = 0; g < 3; ++g) {
      half8 bH = *(half8*)&pB[bf * 6144 + (g * 16 + l15) * 128 + ((qd)     ^ r7) * 16];
      half8 bL = *(half8*)&pB[bf * 6144 + (g * 16 + l15) * 128 + ((qd + 4) ^ r7) * 16];
      accH[g] = __builtin_amdgcn_mfma_f32_16x16x32_f16(aH, bH, accH[g], 0, 0, 0);
      accL[g] = __builtin_amdgcn_mfma_f32_16x16x32_f16(aH, bL, accL[g], 0, 0, 0);
      accL[g] = __builtin_amdgcn_mfma_f32_16x16x32_f16(aL, bH, accL[g], 0, 0, 0);
    }
    if (st < 15) {
      if (st <= 12)      { WAITV(8); }
      else if (st == 13) { WAITV(4); }
      else               { WAITV(0); }
      asm volatile("s_waitcnt lgkmcnt(0)" ::: "memory");
      __builtin_amdgcn_sched_barrier(0);
      __builtin_amdgcn_s_barrier();
    }
  }

  const int v0 = vh * 64 + w * 16 + qd * 4;
#pragma unroll
  for (int g = 0; g < 3; ++g) {
    float bi = b_ih[g * 1024 + C + l15];
#pragma unroll
    for (int i = 0; i < 4; ++i) {
      float val = accH[g][i] + accL[g][i] * LOINV + bi;
      gi[(size_t)(v0 + i) * 3072 + g * 1024 + C + l15] = val;
    }
  }
}

// ----------------------------------------------- persistent two-engine kernel
__global__ __launch_bounds__(256) void k_loop(
    const char* __restrict__ wpre, const char* __restrict__ clsp,
    const float* __restrict__ gi,
    const float* __restrict__ b_hh, const float* __restrict__ cls_b,
    float* __restrict__ hbuf, char* __restrict__ hpre,
    ull* __restrict__ cand, float* __restrict__ out,
    uint32_t* __restrict__ bar)
{
  const int wg = blockIdx.x;
  const int tid = threadIdx.x, lane = tid & 63, w = tid >> 6;
  __shared__ __align__(16) char smem[149504];   // 146KB -> 1 WG/CU

  // once per LAUNCH: agent-scope acquire (L1+L2 inv) -> cross-launch freshness
  if (tid == 0)
    (void)__hip_atomic_load(&bar[576], __ATOMIC_ACQUIRE, __HIP_MEMORY_SCOPE_AGENT);
  __syncthreads();

  uint32_t* hReady = &bar[544];

  const int l15 = lane & 15, qd = lane >> 4, r7 = l15 & 7;
  const int offA_H = (w * 16 + l15) * 128 + ((qd)     ^ r7) * 16;
  const int offA_L = (w * 16 + l15) * 128 + ((qd + 4) ^ r7) * 16;

  if (wg < 128) {
    // =========================== GATES ENGINE ===========================
    const int cg = wg & 63, rh = wg >> 6;
    const int C = cg * 16;
    char* gA = smem;               // 6 * 8192  = 48K
    char* gB = smem + 49152;       // 6 * 6144  = 36K

    for (int s = 1; s < Td; ++s) {
      if (tid == 0)
        while (ld32sys(hReady) < (uint32_t)(s - 1)) __builtin_amdgcn_s_sleep(2);
      __syncthreads();

      const char* hsrc = hpre + (size_t)(s - 1) * HPB + rh * 8192 + w * 2048 + lane * 16;

      f32x4 accH[3], accL[3];
#pragma unroll
      for (int g = 0; g < 3; ++g) {
        accH[g] = (f32x4){0.f, 0.f, 0.f, 0.f};
        accL[g] = (f32x4){0.f, 0.f, 0.f, 0.f};
      }

      auto issue = [&](int st) {   // 3 vmem insts/wave/iter
        const int bf = st % 6;
        char* da = gA + bf * 8192 + w * 2048;
        const char* sa = hsrc + st * 16384;
        dma16(sa, da);
        dma16(sa + 1024, da + 1024);
        const int k0 = 512 + st * 32;
        const int wq = (k0 >= 1152) ? 3 : (k0 >= 768 ? 2 : 1);
        const int wst = (k0 - wq * 384) >> 5;
        const char* sb = wpre + (size_t)((cg * 4 + wq) * 12 + wst) * 6144 + w * 1536 + lane * 16;
        char* db = gB + bf * 6144 + w * 1536;
        dma16(sb, db);
        if (lane < 32) dma16(sb + 1024, db + 1024);
      };

      issue(0); issue(1); issue(2); issue(3); issue(4);

      for (int st = 0; st < 32; ++st) {
        if (st <= 27)      { WAITV(12); }
        else if (st == 28) { WAITV(9); }
        else if (st == 29) { WAITV(6); }
        else if (st == 30) { WAITV(3); }
        else               { WAITV(0); }
        __builtin_amdgcn_s_barrier();

        const int bf = st % 6;
        half8 aH = *(half8*)&gA[bf * 8192 + offA_H];
        half8 aL = *(half8*)&gA[bf * 8192 + offA_L];
        if (st + 5 < 32) issue(st + 5);
#pragma unroll
        for (int g = 0; g < 3; ++g) {
          half8 bH = *(half8*)&gB[bf * 6144 + (g * 16 + l15) * 128 + ((qd)     ^ r7) * 16];
          half8 bL = *(half8*)&gB[bf * 6144 + (g * 16 + l15) * 128 + ((qd + 4) ^ r7) * 16];
          accH[g] = __builtin_amdgcn_mfma_f32_16x16x32_f16(aH, bH, accH[g], 0, 0, 0);
          accL[g] = __builtin_amdgcn_mfma_f32_16x16x32_f16(aH, bL, accL[g], 0, 0, 0);
          accL[g] = __builtin_amdgcn_mfma_f32_16x16x32_f16(aL, bH, accL[g], 0, 0, 0);
        }
      }

      // wait: cls[s-1] candidates complete (tree root == 16 groups)
      if (tid == 0)
        while (ld32sys(&bar[1024 + (s - 1) * 32]) < 16u) __builtin_amdgcn_s_sleep(2);
      __syncthreads();

      // cooperative argmax reduce: 64 rows x 64 candidate slots, 4 thr/row
      uint32_t* sIdx = (uint32_t*)smem;        // 64 entries
      {
        const int row = tid >> 2, sl0 = (tid & 3) * 16;
        const ull* cp = cand + (((size_t)(s - 1) * Bb + rh * 64 + row) * 64 + sl0);
        ull best = 0ull;
#pragma unroll
        for (int k = 0; k < 16; ++k) best = umax64(best, cp[k]);
        best = umax64(best, __shfl_xor(best, 1));
        best = umax64(best, __shfl_xor(best, 2));
        if ((tid & 3) == 0) sIdx[row] = (~(uint32_t)best) & 8191u;
      }
      __syncthreads();

      // GRU epilogue: 4 rows x 1 col per lane
      const int j = C + l15;
      const float bh0 = b_hh[j], bh1 = b_hh[1024 + j], bh2 = b_hh[2048 + j];
      const float* hprev_f = hbuf + (size_t)((s - 1) & 1) * Bb * Hd;
      float* hnew_f = hbuf + (size_t)(s & 1) * Bb * Hd;
      float outs[4];
#pragma unroll
      for (int i = 0; i < 4; ++i) {
        const int lr = w * 16 + qd * 4 + i;    // local row 0..63
        const int ri = rh * 64 + lr;
        const uint32_t idx = sIdx[lr];
        const float* gp = gi + (size_t)idx * 3072 + j;
        float i_r = gp[0], i_z = gp[1024], i_n = gp[2048];
        float h_r = accH[0][i] + accL[0][i] * LOINV + bh0;
        float h_z = accH[1][i] + accL[1][i] * LOINV + bh1;
        float h_n = accH[2][i] + accL[2][i] * LOINV + bh2;
        float rr2 = 1.f / (1.f + expf(-(i_r + h_r)));
        float zz = 1.f / (1.f + expf(-(i_z + h_z)));
        float nn = tanhf(i_n + rr2 * h_n);
        float o = (1.f - zz) * nn + zz * hprev_f[ri * Hd + j];
        hnew_f[ri * Hd + j] = o;          // WG-private slice (persistent WG)
        outs[i] = o;
      }
      // transpose via LDS -> 16B write-through hpre stores
      __syncthreads();
      float* sT = (float*)(smem + 4096);
#pragma unroll
      for (int i = 0; i < 4; ++i)
        sT[(w * 16 + qd * 4 + i) * 16 + l15] = outs[i];
      __syncthreads();
      if (tid < 128) {
        const int row = tid >> 1, half = tid & 1;
        const int b = rh * 64 + row;
        const float* srcp = sT + row * 16 + half * 8;
        half8 hh, ll;
#pragma unroll
        for (int e = 0; e < 8; ++e) {
          float o = srcp[e];
          _Float16 oh = (_Float16)o;
          hh[e] = oh;
          ll[e] = (_Float16)((o - (float)oh) * LOSCALE);
        }
        const int stp = C >> 5;
        const int chb = ((C & 31) >> 3) + half;
        char* hp = hpre + (size_t)s * HPB + stp * 16384 + b * 128;
        st16sc(hp + ((chb       ^ (b & 7))) * 16, hh);
        st16sc(hp + (((chb + 4) ^ (b & 7))) * 16, ll);
      }
      WAITV(0);              // hpre + hbuf stores complete
      __syncthreads();
      if (tid == 0) {
        // two-level completion tree: 16 groups of 8 -> root -> hReady
        uint32_t old = add32sys(&bar[(wg >> 3) * 32], 1u);
        if (old + 1u == 8u * (uint32_t)s) {
          uint32_t o2 = add32sys(&bar[512], 1u);
          if (o2 + 1u == 16u * (uint32_t)s)
            st32sys(hReady, (uint32_t)s);   // releases cls[s] + gates[s+1]
        }
      }
    }
  } else {
    // ============================ CLS ENGINE ============================
    const int wgC = wg - 128;
    const int ct2 = wgC & 63, rt0 = wgC >> 6;
    const int r0c = rt0 * 64;
    char* cA = smem;               // 6 * 8192  = 48K
    char* cB = smem + 49152;       // 6 * 16384 = 96K
    const char* bb0 = clsp + (size_t)(2 * ct2)     * 262144 + w * 2048 + lane * 16;
    const char* bb1 = clsp + (size_t)(2 * ct2 + 1) * 262144 + w * 2048 + lane * 16;

    for (int s = 1; s < Td; ++s) {
      if (tid == 0)
        while (ld32sys(hReady) < (uint32_t)s) __builtin_amdgcn_s_sleep(2);
      __syncthreads();

      const char* asrc = hpre + (size_t)s * HPB + rt0 * 8192 + w * 2048 + lane * 16;

      f32x4 accH[8], accL[8];
#pragma unroll
      for (int i = 0; i < 8; ++i) {
        accH[i] = (f32x4){0.f, 0.f, 0.f, 0.f};
        accL[i] = (f32x4){0.f, 0.f, 0.f, 0.f};
      }

      auto issue = [&](int st) {   // 6 vmem insts/wave/iter
        const int bf = st % 6;
        char* da = cA + bf * 8192 + w * 2048;
        const char* sa = asrc + st * 16384;
        dma16(sa, da);
        dma16(sa + 1024, da + 1024);
        char* db = cB + bf * 16384 + w * 2048;
        const char* s0 = bb0 + st * 8192;
        dma16(s0, db);
        dma16(s0 + 1024, db + 1024);
        const char* s1 = bb1 + st * 8192;
        dma16(s1, db + 8192);
        dma16(s1 + 1024, db + 8192 + 1024);
      };

      issue(0); issue(1); issue(2); issue(3); issue(4);

      for (int st = 0; st < 32; ++st) {
        if (st <= 27)      { WAITV(24); }
        else if (st == 28) { WAITV(18); }
        else if (st == 29) { WAITV(12); }
        else if (st == 30) { WAITV(6); }
        else               { WAITV(0); }
        __builtin_amdgcn_s_barrier();

        const int bf = st % 6;
        half8 aH = *(half8*)&cA[bf * 8192 + offA_H];
        half8 aL = *(half8*)&cA[bf * 8192 + offA_L];
        if (st + 5 < 32) issue(st + 5);
#pragma unroll
        for (int cf = 0; cf < 8; ++cf) {
          const int bo = bf * 16384 + (cf >> 2) * 8192 + ((cf & 3) * 16 + l15) * 128;
          half8 bH = *(half8*)&cB[bo + ((qd)     ^ r7) * 16];
          half8 bL = *(half8*)&cB[bo + ((qd + 4) ^ r7) * 16];
          accH[cf] = __builtin_amdgcn_mfma_f32_16x16x32_f16(aH, bH, accH[cf], 0, 0, 0);
          accL[cf] = __builtin_amdgcn_mfma_f32_16x16x32_f16(aH, bL, accL[cf], 0, 0, 0);
          accL[cf] = __builtin_amdgcn_mfma_f32_16x16x32_f16(aL, bH, accL[cf], 0, 0, 0);
        }
      }

      // epilogue: +bias, nontemporal logit stores, plain candidate stores
      float bsv[8];
#pragma unroll
      for (int cf = 0; cf < 8; ++cf)
        bsv[cf] = cls_b[(2 * ct2 + (cf >> 2)) * 64 + (cf & 3) * 16 + l15];
#pragma unroll
      for (int i = 0; i < 4; ++i) {
        const int brow = r0c + w * 16 + qd * 4 + i;
        float* orow = out + ((size_t)brow * Td + s) * Vd;
        ull best = 0ull;
#pragma unroll
        for (int cf = 0; cf < 8; ++cf) {
          const int v = (2 * ct2 + (cf >> 2)) * 64 + (cf & 3) * 16 + l15;
          float val = accH[cf][i] + accL[cf][i] * LOINV + bsv[cf];
          __builtin_nontemporal_store(val, &orow[v]);
          best = umax64(best, ((ull)fkey(val) << 32) | (uint32_t)(~(uint32_t)v));
        }
        best = umax64(best, __shfl_xor(best, 1));
        best = umax64(best, __shfl_xor(best, 2));
        best = umax64(best, __shfl_xor(best, 4));
        best = umax64(best, __shfl_xor(best, 8));
        if (l15 == 0)
          st8sc(&cand[(((size_t)s * Bb + brow) * 64 + ct2)], best);
      }
      WAITV(0);              // logits + candidate stores complete
      __syncthreads();
      if (tid == 0) {
        // two-level: 16 groups of 8 -> aRoot[s]
        uint32_t old = add32sys(&bar[8192 + ((s * 16) + (wgC >> 3)) * 32], 1u);
        if (old + 1u == 8u)
          add32sys(&bar[1024 + s * 32], 1u);   // aRoot[s] -> 16 when done
      }
    }
  }
}

// -------------------------------------------------- final log_softmax pass
__global__ void k_softmax(float* __restrict__ out,
                          const ull* __restrict__ cand) {
  int blk = blockIdx.x;           // 12800 = 128*100
  int t = blk % Td, b = blk / Td;
  int tid = threadIdx.x;
  float* row = out + ((size_t)b * Td + t) * Vd;
  if (t == 0) {
    float lse0 = logf(expf(1.0f) + (float)(Vd - 1));
    for (int i = tid; i < Vd; i += 256) row[i] = ((i == 0) ? 1.0f : 0.0f) - lse0;
    return;
  }
  // reduce 64 candidate slots (per-wave, redundant across the 4 waves)
  ull key = cand[((size_t)t * Bb + b) * 64 + (tid & 63)];
  key = umax64(key, __shfl_xor(key, 1));
  key = umax64(key, __shfl_xor(key, 2));
  key = umax64(key, __shfl_xor(key, 4));
  key = umax64(key, __shfl_xor(key, 8));
  key = umax64(key, __shfl_xor(key, 16));
  key = umax64(key, __shfl_xor(key, 32));
  uint32_t ku = (uint32_t)(key >> 32);
  uint32_t u = (ku & 0x80000000u) ? (ku & 0x7fffffffu) : ~ku;
  float m = __uint_as_float(u);
  float x[32];
  float ssum = 0.f;
#pragma unroll
  for (int i = 0; i < 32; ++i) {
    x[i] = row[tid + i * 256];
    ssum += expf(x[i] - m);
  }
  ssum += __shfl_xor(ssum, 1);
  ssum += __shfl_xor(ssum, 2);
  ssum += __shfl_xor(ssum, 4);
  ssum += __shfl_xor(ssum, 8);
  ssum += __shfl_xor(ssum, 16);
  ssum += __shfl_xor(ssum, 32);
  __shared__ float wsum[4];
  if ((tid & 63) == 0) wsum[tid >> 6] = ssum;
  __syncthreads();
  float lse = m + logf(wsum[0] + wsum[1] + wsum[2] + wsum[3]);
#pragma unroll
  for (int i = 0; i < 32; ++i) row[tid + i * 256] = x[i] - lse;
}

// ----------------------------------------------------------------- launch
extern "C" void kernel_launch(void* const* d_in, const int* in_sizes, int n_in,
                              void* d_out, int out_size, void* d_ws, size_t ws_size,
                              hipStream_t stream) {
  const float* x     = (const float*)d_in[0];
  const float* emb   = (const float*)d_in[1];
  const float* w_ih  = (const float*)d_in[2];
  const float* w_hh  = (const float*)d_in[3];
  const float* b_ih  = (const float*)d_in[4];
  const float* b_hh  = (const float*)d_in[5];
  const float* cls_w = (const float*)d_in[6];
  const float* cls_b = (const float*)d_in[7];
  float* out = (float*)d_out;

  char* ws = (char*)d_ws;
  size_t o = 0;
  ull*      cand = (ull*)(ws + o);      o += (size_t)Td * Bb * 64 * 8;  // 6.55 MB
  uint32_t* bar  = (uint32_t*)(ws + o); o += (size_t)BAR_WORDS * 4;     // 256 KB
  float*    hbuf = (float*)(ws + o);    o += (size_t)2 * Bb * Hd * 4;   // 1 MB
  char*     hpre = ws + o;              o += (size_t)Td * HPB;          // 52.4 MB
  char*     embp = ws + o;              o += (size_t)Vd * 2048;         // 16.8 MB
  char*     wpre = ws + o;              o += (size_t)3072 * 6144;       // 18.9 MB
  char*     clsp = ws + o;              o += (size_t)128 * 32 * 8192;   // 33.6 MB
  float*    gi   = (float*)(ws + o);    o += (size_t)Vd * 3072 * 4;     // 100.7 MB

  k_init<<<512, 256, 0, stream>>>(x, hbuf, cand, hpre, bar);
  k_prep_emb<<<2048, 256, 0, stream>>>(emb, embp);
  k_prep_w<<<3072, 256, 0, stream>>>(w_ih, w_hh, wpre);
  k_prep_cls<<<4096, 256, 0, stream>>>(cls_w, clsp);
  k_prep_gi<<<dim3(64, 128), 256, 0, stream>>>(embp, wpre, b_ih, gi);

  k_loop<<<256, 256, 0, stream>>>(wpre, clsp, gi, b_hh, cls_b,
                                  hbuf, hpre, cand, out, bar);

  k_softmax<<<12800, 256, 0, stream>>>(out, cand);
}